// Round 3
// baseline (1187.942 us; speedup 1.0000x reference)
//
#include <hip/hip_runtime.h>
#include <hip/hip_bf16.h>

// Non-local means, 8x3x512x512 fp32, search 21x21 (R=10), patch 7x7 (PR=3),
// circular wrap everywhere (jnp.roll semantics).
//
// Per block: 64x32 output tile. Shift loop inside kernel.
// Phase 1: vertical 7-box-sum of (y - shifted y)^2, register sliding, column strips.
// Phase 2: horizontal 7-sum sliding + sqrt/exp + accumulate (num RGB, den) in VGPRs.

#define IMG    512
#define HW     (IMG*IMG)
#define TW     64
#define TH     32
#define RWIN   10
#define HALO   13              // RWIN + PR
#define YROWS  59              // TH + 2*HALO + 1 fake row
#define YCOLS  90              // TW + 2*HALO
#define YSTR   59              // odd stride, y stored transposed [col][row]
#define VROWS  33              // 32 + 1 fake row (strip rg=2 writes one junk row)
#define VSTR   71              // 70 cols (-3..66) + 1 pad
#define RGROWS 52              // TH + 2*RWIN
#define RGCOLS 84              // TW + 2*RWIN
#define RGSTR  86
#define RGPL   (RGROWS*RGSTR)  // 4472 elems per bf16 plane

__launch_bounds__(256)
__global__ void nlm_kernel(const float* __restrict__ rgb,
                           const float* __restrict__ hptr,
                           float* __restrict__ out)
{
    __shared__ float          y_t[YCOLS * YSTR];   // 21240 B
    __shared__ __hip_bfloat16 rgl[3 * RGPL];       // 26832 B
    __shared__ float          vert[VROWS * VSTR];  //  9372 B   (total 57444 B)

    const int tid = threadIdx.x;
    const int tx  = blockIdx.x;   // 0..7
    const int ty  = blockIdx.y;   // 0..15
    const int b   = blockIdx.z;   // 0..7

    const float hval  = hptr[0];
    const float inv_h = 1.0f / (fmaxf(hval, 0.0f) + 1e-8f);
    const float sc    = -inv_h * 1.4426950408889634f;   // for exp2

    // ---------------- stage y (fp32 transposed) + rgb (bf16 planes) ----------------
    const size_t ibase = (size_t)b * 3 * HW;
    const int row0 = ty*TH - HALO;
    const int col0 = tx*TW - HALO;
    for (int i = tid; i < 58*90; i += 256) {
        int rr = i / 90;
        int cc = i - rr*90;
        int gr = (row0 + rr) & (IMG-1);
        int gc = (col0 + cc) & (IMG-1);
        size_t g = ibase + (size_t)gr*IMG + gc;
        float R  = fminf(fmaxf(rgb[g         ], 0.f), 1.f);
        float G  = fminf(fmaxf(rgb[g +     HW], 0.f), 1.f);
        float Bv = fminf(fmaxf(rgb[g + 2 * HW], 0.f), 1.f);
        y_t[cc*YSTR + rr] = 0.299f*R + 0.587f*G + 0.114f*Bv;
        int r2 = rr - 3, c2 = cc - 3;
        if ((unsigned)r2 < RGROWS && (unsigned)c2 < RGCOLS) {
            int o = r2*RGSTR + c2;
            rgl[o         ] = __float2bfloat16(R);
            rgl[o +   RGPL] = __float2bfloat16(G);
            rgl[o + 2*RGPL] = __float2bfloat16(Bv);
        }
    }
    __syncthreads();

    // ---------------- phase-1 statics: 210 column strips (70 cols x 3 rowgroups) ----
    const int p1col = tid % 70;       // 0..69 (valid when tid<210)
    const int p1rg  = tid / 70;       // 0..2
    const int r0    = p1rg * 11;      // strip rows r0..r0+10 (rg2 row 32 is junk)
    const int p1base = (p1col + 10)*YSTR + (r0 + 10);
    float yown[17];
    if (tid < 210) {
        #pragma unroll
        for (int k = 0; k < 17; ++k)
            yown[k] = y_t[p1base + k];
    }

    // ---------------- phase-2 statics: row r, cols c0..c0+7 -------------------------
    const int r   = tid >> 3;         // 0..31
    const int c0  = (tid & 7) * 8;    // 0..56
    const int vbase  = r*VSTR + c0;   // reads vp[0..13] == vert cols c0-3..c0+10
    const int rgbase = (r + 10)*RGSTR + (c0 + 10);

    float aR[8], aG[8], aB[8], aD[8];
    #pragma unroll
    for (int j = 0; j < 8; ++j) { aR[j]=0.f; aG[j]=0.f; aB[j]=0.f; aD[j]=0.f; }

    // ---------------- shift loop ----------------------------------------------------
    #pragma unroll 1
    for (int dy = -RWIN; dy <= RWIN; ++dy) {
        #pragma unroll 1
        for (int dx = -RWIN; dx <= RWIN; ++dx) {
            // phase 1: vertical 7-box of (y - y_shifted)^2, register slide
            if (tid < 210) {
                const float* ys = &y_t[p1base - dx*YSTR - dy];
                float d[17];
                #pragma unroll
                for (int k = 0; k < 17; ++k) {
                    float t = yown[k] - ys[k];
                    d[k] = t*t;
                }
                float v = d[0]+d[1]+d[2]+d[3]+d[4]+d[5]+d[6];
                float* vp = &vert[r0*VSTR + p1col];
                vp[0] = v;
                #pragma unroll
                for (int j = 1; j < 11; ++j) {
                    v += d[j+6] - d[j-1];
                    vp[j*VSTR] = v;
                }
            }
            __syncthreads();
            // phase 2: horizontal 7-sum slide, weight, accumulate
            {
                const float* vp = &vert[vbase];
                const __hip_bfloat16* rb = &rgl[rgbase - dy*RGSTR - dx];
                float hacc = vp[0]+vp[1]+vp[2]+vp[3]+vp[4]+vp[5]+vp[6];
                #pragma unroll
                for (int j = 0; j < 8; ++j) {
                    if (j) hacc += vp[j+6] - vp[j-1];
                    float dist = __builtin_amdgcn_sqrtf(fmaxf(hacc, 0.0f));
                    float w    = __builtin_amdgcn_exp2f(dist * sc);
                    aR[j] += w * __bfloat162float(rb[j         ]);
                    aG[j] += w * __bfloat162float(rb[j +   RGPL]);
                    aB[j] += w * __bfloat162float(rb[j + 2*RGPL]);
                    aD[j] += w;
                }
            }
            __syncthreads();
        }
    }

    // ---------------- epilogue ------------------------------------------------------
    const int gr = ty*TH + r;
    const int gc = tx*TW + c0;
    float* op = out + ibase + (size_t)gr*IMG + gc;
    #pragma unroll
    for (int j = 0; j < 8; ++j) {
        float iv = 1.0f / aD[j];
        op[j         ] = fminf(fmaxf(aR[j]*iv, 0.f), 1.f);
        op[j +     HW] = fminf(fmaxf(aG[j]*iv, 0.f), 1.f);
        op[j + 2 * HW] = fminf(fmaxf(aB[j]*iv, 0.f), 1.f);
    }
}

extern "C" void kernel_launch(void* const* d_in, const int* in_sizes, int n_in,
                              void* d_out, int out_size, void* d_ws, size_t ws_size,
                              hipStream_t stream) {
    const float* rgb = (const float*)d_in[0];
    const float* h   = (const float*)d_in[1];
    float* out       = (float*)d_out;
    dim3 grid(IMG/TW, IMG/TH, 8);   // 8 x 16 x 8 = 1024 blocks
    nlm_kernel<<<grid, 256, 0, stream>>>(rgb, h, out);
}

// Round 5
// 1063.549 us; speedup vs baseline: 1.1170x; 1.1170x over previous
//
#include <hip/hip_runtime.h>
#include <hip/hip_bf16.h>
#include <hip/hip_fp16.h>

// Non-local means, 8x3x512x512 fp32, search 21x21 (R=10), patch 7x7 (PR=3),
// circular wrap (jnp.roll semantics).
//
// v2: dx-outer/dy-inner with register-sliding shifted-y window (phase-1 LDS
// reads 17->1 per step); RGBY packed 8B/pixel LDS (phase-2 rgb reads 24 u16
// -> 8 ds_read2_b32); 52.6 KB LDS -> 3 blocks/CU.

#define IMG   512
#define HW    (IMG*IMG)
#define TW    64
#define TH    32
#define RWIN  10
#define HALO  13              // RWIN + PR
#define PROWS 59              // staged rows 0..58 (58 real + 1 for junk strip row)
#define PCOLS 91              // staged cols 0..90 (reads use 0..89)
#define PSTR  183             // WORDS per pixel row (odd -> conflict-spread)
#define VSTR  71              // vert: 70 cols (-3..66) + 1 pad, odd
#define VROWS 33              // 32 + 1 junk row from strip rg=2

__device__ __forceinline__ uint32_t f2bf(float x) {   // f32 -> bf16 bits (RNE)
    uint32_t u = __float_as_uint(x);
    return (u + 0x7fffu + ((u >> 16) & 1u)) >> 16;
}

// Y (fp16) lives in hi16 of word1 of each 8B pixel
#define LDY(row, col) \
    __half2float(((const __half*)pixw)[((((row)*PSTR + (col)*2 + 1)) << 1) | 1])

__launch_bounds__(256, 3)
__global__ void nlm_kernel(const float* __restrict__ rgb,
                           const float* __restrict__ hptr,
                           float* __restrict__ out)
{
    __shared__ uint32_t pixw[PROWS * PSTR];   // 43188 B : {R|G<<16, B|Y<<16} per pixel
    __shared__ float    vert[VROWS * VSTR];   //  9372 B   (total 52560 B -> 3 blk/CU)

    const int tid = threadIdx.x;
    const int tx  = blockIdx.x;   // 0..7
    const int ty  = blockIdx.y;   // 0..15
    const int b   = blockIdx.z;   // 0..7

    const float hval  = hptr[0];
    const float inv_h = 1.0f / (fmaxf(hval, 0.0f) + 1e-8f);
    const float sc    = -inv_h * 1.4426950408889634f;   // exp2 scale

    // ---------------- stage packed RGBY ------------------------------------
    const size_t ibase = (size_t)b * 3 * HW;
    const int row0 = ty*TH - HALO;
    const int col0 = tx*TW - HALO;
    for (int i = tid; i < PROWS*PCOLS; i += 256) {
        int rr = i / PCOLS;
        int cc = i - rr*PCOLS;
        int gr = (row0 + rr) & (IMG-1);
        int gc = (col0 + cc) & (IMG-1);
        size_t g = ibase + (size_t)gr*IMG + gc;
        float R  = fminf(fmaxf(rgb[g         ], 0.f), 1.f);
        float G  = fminf(fmaxf(rgb[g +     HW], 0.f), 1.f);
        float Bv = fminf(fmaxf(rgb[g + 2 * HW], 0.f), 1.f);
        float Y  = 0.299f*R + 0.587f*G + 0.114f*Bv;
        int o = rr*PSTR + cc*2;
        pixw[o    ] = f2bf(R) | (f2bf(G) << 16);
        pixw[o + 1] = f2bf(Bv) | ((uint32_t)__half_as_ushort(__float2half(Y)) << 16);
    }
    __syncthreads();

    // ---------------- phase-1 statics: 210 column strips --------------------
    const int  c  = tid % 70;         // vert col slot (abs tile col c-3)
    const int  rg = tid / 70;         // 0..2
    const int  r0 = rg * 11;          // vert rows r0..r0+10 (rg=2 row 32 junk)
    const bool p1 = tid < 210;
    float yown[17];
    if (p1) {
        #pragma unroll
        for (int k = 0; k < 17; ++k)
            yown[k] = LDY(r0 + 10 + k, c + 10);     // abs rows r0-3..r0+13
    }

    // ---------------- phase-2 statics ---------------------------------------
    const int r   = tid >> 3;         // 0..31
    const int c0  = (tid & 7) * 8;    // 0..56
    const int vb2 = r*VSTR + c0;      // vp[0..13] = vert cols c0-3..c0+10

    float aR[8], aG[8], aB[8], aD[8];
    #pragma unroll
    for (int j = 0; j < 8; ++j) { aR[j]=0.f; aG[j]=0.f; aB[j]=0.f; aD[j]=0.f; }

    // ---------------- shift loop: dx outer, dy inner ------------------------
    #pragma unroll 1
    for (int dx = -RWIN; dx <= RWIN; ++dx) {
        const int cs = c + 10 - dx;               // shifted y column (0..89)
        float ys[17];                             // ys[k] = Y[r0+10+k-dy] (sliding)
        if (p1) {
            #pragma unroll
            for (int k = 0; k < 17; ++k)
                ys[k] = LDY(r0 + 20 + k, cs);     // fill for dy=-10
        }
        #pragma unroll 3
        for (int dy = -RWIN; dy <= RWIN; ++dy) {
            // ---- phase 1: vertical 7-box of (y - y_shifted)^2 ----
            if (p1) {
                float d[17];
                #pragma unroll
                for (int k = 0; k < 17; ++k) {
                    float t = yown[k] - ys[k];
                    d[k] = t*t;
                }
                float v = d[0]+d[1]+d[2]+d[3]+d[4]+d[5]+d[6];
                int vb = r0*VSTR + c;
                vert[vb] = v;
                #pragma unroll
                for (int j = 1; j < 11; ++j) {
                    v += d[j+6] - d[j-1];
                    vert[vb + j*VSTR] = v;
                }
            }
            __syncthreads();
            // ---- phase 2: horizontal 7-slide + weight + accumulate ----
            {
                const float* vp = &vert[vb2];
                float hacc = vp[0]+vp[1]+vp[2]+vp[3]+vp[4]+vp[5]+vp[6];
                const int prow  = r - dy + HALO;          // 3..54
                const int pb    = prow*PSTR + (c0 - dx + HALO)*2;
                #pragma unroll
                for (int j = 0; j < 8; ++j) {
                    if (j) hacc += vp[j+6] - vp[j-1];
                    float dist = __builtin_amdgcn_sqrtf(fmaxf(hacc, 0.0f));
                    float w    = __builtin_amdgcn_exp2f(dist * sc);
                    uint32_t w0 = pixw[pb + 2*j    ];
                    uint32_t w1 = pixw[pb + 2*j + 1];
                    float R  = __uint_as_float(w0 << 16);
                    float G  = __uint_as_float(w0 & 0xffff0000u);
                    float Bv = __uint_as_float(w1 << 16);
                    aR[j] += w * R;
                    aG[j] += w * G;
                    aB[j] += w * Bv;
                    aD[j] += w;
                }
            }
            __syncthreads();
            // ---- slide shifted-y window down one row for next dy ----
            if (p1 && dy < RWIN) {
                #pragma unroll
                for (int k = 16; k >= 1; --k) ys[k] = ys[k-1];
                ys[0] = LDY(r0 + 9 - dy, cs);
            }
        }
    }

    // ---------------- epilogue ----------------------------------------------
    const int gr = ty*TH + r;
    const int gc = tx*TW + c0;
    float* op = out + ibase + (size_t)gr*IMG + gc;
    #pragma unroll
    for (int j = 0; j < 8; ++j) {
        float iv = 1.0f / aD[j];
        op[j         ] = fminf(fmaxf(aR[j]*iv, 0.f), 1.f);
        op[j +     HW] = fminf(fmaxf(aG[j]*iv, 0.f), 1.f);
        op[j + 2 * HW] = fminf(fmaxf(aB[j]*iv, 0.f), 1.f);
    }
}

extern "C" void kernel_launch(void* const* d_in, const int* in_sizes, int n_in,
                              void* d_out, int out_size, void* d_ws, size_t ws_size,
                              hipStream_t stream) {
    const float* rgb = (const float*)d_in[0];
    const float* h   = (const float*)d_in[1];
    float* out       = (float*)d_out;
    dim3 grid(IMG/TW, IMG/TH, 8);   // 8 x 16 x 8 = 1024 blocks
    nlm_kernel<<<grid, 256, 0, stream>>>(rgb, h, out);
}